// Round 1
// baseline (246.018 us; speedup 1.0000x reference)
//
#include <hip/hip_runtime.h>

// PostProcessor3D: threshold(>0.9) + 5x5x5 stride-1 maxpool + strict-local-max
// mask on [64,512,512] fp32.
//
// R12: attack the latency-bound regime (R11: 45-48 us, no pipe >40%,
// occupancy 21%). Traffic is already ~ideal (138 MB vs 134 MB floor), so the
// only lever left is CONCURRENCY:
//  (a) DCHUNK 16->8: grid 1024 -> 2048 blocks (8 geometric blocks/CU).
//      Z-halo refetch rises (12 staged slices per 8 outputs) but z-neighbor
//      blocks are 256 apart => same XCD under round-robin dispatch => halo
//      slices L2-shared.
//  (b) __launch_bounds__(256, 8): cap VGPRs at 64 so 8 blocks/CU are
//      actually resident (76 regs previously quantized to the 4-waves/SIMD
//      bucket -- measured occupancy steps at 64/128/256).
//  (c) Register diet to make 64 feasible: cen ring 5->3 deep (write@t,
//      read slice t-2 => depth 3), int (not size_t) global offsets.
// Everything else is R11's proven structure: raw-max trick (no thresholding
// in the hot loop), ONE lgkmcnt-only barrier + ONE LDS round-trip per slice,
// H-max direct from LDS + halo column reads, W-max via 4 shuffles, dist-2
// register prefetch, fully unrolled loop (NS=12) for compile-time ring
// indices.
//
// Tile: W=64 x H=16, DCHUNK=8 -> grid 8x32x8 = 2048 blocks, 8/CU.

#define THRESH 0.9f

constexpr int D = 64, H = 512, W = 512;
constexpr int HW = H * W;
constexpr int TW = 64;                    // tile width in floats
constexpr int TH = 16;                    // tile height
constexpr int DCHUNK = 8;                 // depth outputs per block
constexpr int HALO = 2;
constexpr int LROWS = TH + 2 * HALO;      // 20 staged rows
constexpr int RAWQ  = TW / 4 + 2;         // 18 quads/row: [w0-4, w0+68)
constexpr int RAW_S = RAWQ + 1;           // 19: de-phase rows
constexpr int NS = DCHUNK + 2 * HALO;     // 12 slices per block

typedef float floatx4 __attribute__((ext_vector_type(4)));

__device__ __forceinline__ void barrier_no_drain() {
    asm volatile("s_waitcnt lgkmcnt(0)\n\ts_barrier" ::: "memory");
}

__device__ __forceinline__ float4 max4(float4 a, float4 b) {
    return make_float4(fmaxf(a.x, b.x), fmaxf(a.y, b.y),
                       fmaxf(a.z, b.z), fmaxf(a.w, b.w));
}

// 5-tap sliding max for one quad. b = own (f4..f7), f2,f3 = left neighbor's
// .z,.w; f8,f9 = right neighbor's .x,.y. out[j] = max over [4c+j-2, 4c+j+2].
__device__ __forceinline__ float4 wmax5s(float f2, float f3, float4 b,
                                         float f8, float f9) {
    const float f4 = b.x, f5 = b.y, f6 = b.z, f7 = b.w;
    const float m45 = fmaxf(f4, f5);
    const float m56 = fmaxf(f5, f6);
    const float m345 = fmaxf(f3, m45);
    const float m456 = fmaxf(f4, m56);
    const float m567 = fmaxf(m56, f7);
    const float m678 = fmaxf(fmaxf(f6, f7), f8);
    float4 r;
    r.x = fmaxf(fmaxf(f2, f6), m345);
    r.y = fmaxf(fmaxf(f3, f7), m456);
    r.z = fmaxf(fmaxf(f4, f8), m567);
    r.w = fmaxf(fmaxf(f5, f9), m678);
    return r;
}

__global__ __launch_bounds__(256, 8)
void peak3d_kernel(const float* __restrict__ in, float* __restrict__ out) {
    __shared__ float4 raw[2][LROWS * RAW_S];  // 2 x 380 quads = 12160 B

    const int tx = threadIdx.x;               // 0..15 (quad col)
    const int ty = threadIdx.y;               // 0..15 (row)
    const int tid = ty * 16 + tx;

    const int w0 = blockIdx.x * TW;
    const int h0 = blockIdx.y * TH;
    const int d0 = blockIdx.z * DCHUNK;

    // Staging map: 20 rows x 18 quads = 360 quads, <=2 per thread.
    const int q0 = tid;
    const int q1 = tid + 256;
    const int r0 = q0 / RAWQ, c0 = q0 % RAWQ;
    const int r1 = q1 / RAWQ, c1 = q1 % RAWQ;
    const int lds0 = r0 * RAW_S + c0;
    const int lds1 = r1 * RAW_S + c1;
    const int gh0 = h0 + r0 - HALO, gw0 = w0 + 4 * c0 - 4;
    const int gh1 = h0 + r1 - HALO, gw1 = w0 + 4 * c1 - 4;
    const bool has1 = (q1 < LROWS * RAWQ);
    const bool ib0 = (gh0 >= 0 && gh0 < H && gw0 >= 0 && gw0 < W);
    const bool ib1 = has1 && (gh1 >= 0 && gh1 < H && gw1 >= 0 && gw1 < W);
    const int off0 = ib0 ? (gh0 * W + gw0) : 0;   // slice-local, fits int
    const int off1 = ib1 ? (gh1 * W + gw1) : 0;

    const float4 zero4 = make_float4(0.f, 0.f, 0.f, 0.f);
    float4 win[5];                            // HW-max ring, depth 5 (D window)
    float4 cen[3];                            // raw center ring, depth 3
#pragma unroll
    for (int k = 0; k < 5; ++k) win[k] = zero4;
#pragma unroll
    for (int k = 0; k < 3; ++k) cen[k] = zero4;

    auto loadSlice = [&](int dd, float4& a, float4& b) {  // RAW (no thresh)
        a = zero4; b = zero4;
        if (dd >= 0 && dd < D) {
            const int base = dd * HW;         // < 2^24, fits int
            if (ib0) a = *reinterpret_cast<const float4*>(in + base + off0);
            if (ib1) b = *reinterpret_cast<const float4*>(in + base + off1);
        }
    };

    // Distance-2 register prefetch.
    float4 pfa[2], pfb[2];
    loadSlice(d0 - HALO + 0, pfa[0], pfb[0]);
    loadSlice(d0 - HALO + 1, pfa[1], pfb[1]);

    // Consume-phase LDS column for the halo H-max (left edge / right edge).
    const int hcol = (tx == 0) ? 0 : (RAWQ - 1);   // 0 or 17

#pragma unroll
    for (int t = 0; t < NS; ++t) {            // fully unrolled: t constant
        const int buf = t & 1;

        // ---- stage slice t (raw values), refill slot with slice t+2 ----
        raw[buf][lds0] = pfa[buf];
        if (has1) raw[buf][lds1] = pfb[buf];
        if (t + 2 < NS) loadSlice(d0 - HALO + t + 2, pfa[buf], pfb[buf]);

        barrier_no_drain();                   // the only barrier per slice

        // ---- consume: H-max (5 rows) + halo + W-max via shuffles ----
        const float4* bp = &raw[buf][0];
        const float4 r0q = bp[(ty + 0) * RAW_S + (tx + 1)];
        const float4 r1q = bp[(ty + 1) * RAW_S + (tx + 1)];
        const float4 r2q = bp[(ty + 2) * RAW_S + (tx + 1)];  // center row
        const float4 r3q = bp[(ty + 3) * RAW_S + (tx + 1)];
        const float4 r4q = bp[(ty + 4) * RAW_S + (tx + 1)];
        const float4 hv = max4(max4(max4(r0q, r1q), max4(r3q, r4q)), r2q);

        const float4 e0 = bp[(ty + 0) * RAW_S + hcol];
        const float4 e1 = bp[(ty + 1) * RAW_S + hcol];
        const float4 e2 = bp[(ty + 2) * RAW_S + hcol];
        const float4 e3 = bp[(ty + 3) * RAW_S + hcol];
        const float4 e4 = bp[(ty + 4) * RAW_S + hcol];
        const float4 hq = max4(max4(max4(e0, e1), max4(e3, e4)), e2);

        float f2 = __shfl_up(hv.z, 1);        // left neighbor (same row-group)
        float f3 = __shfl_up(hv.w, 1);
        float f8 = __shfl_down(hv.x, 1);      // right neighbor
        float f9 = __shfl_down(hv.y, 1);
        if (tx == 0)  { f2 = hq.z; f3 = hq.w; }   // left halo quad (col 0)
        if (tx == 15) { f8 = hq.x; f9 = hq.y; }   // right halo quad (col 17)

        win[t % 5] = wmax5s(f2, f3, hv, f8, f9);  // HW-max, slice t
        cen[t % 3] = r2q;                          // raw center row, slice t

        // ---- D-max + strict-local-max + store (slice t-2 center) ----
        if (t >= 4) {
            const int dout = d0 + (t - 4);    // = (d0-2+t) - 2, window center
            const float4 mp = max4(max4(max4(win[0], win[1]),
                                        max4(win[2], win[3])), win[4]);
            const float4 c = cen[(t + 1) % 3];     // written at iter t-2
            floatx4 res;
            res.x = (c.x > THRESH && mp.x == c.x) ? c.x : 0.f;
            res.y = (c.y > THRESH && mp.y == c.y) ? c.y : 0.f;
            res.z = (c.z > THRESH && mp.z == c.z) ? c.z : 0.f;
            res.w = (c.w > THRESH && mp.w == c.w) ? c.w : 0.f;
            floatx4* op = reinterpret_cast<floatx4*>(
                out + (size_t)dout * HW + (size_t)(h0 + ty) * W + (w0 + 4 * tx));
            __builtin_nontemporal_store(res, op);
        }
    }
}

extern "C" void kernel_launch(void* const* d_in, const int* in_sizes, int n_in,
                              void* d_out, int out_size, void* d_ws, size_t ws_size,
                              hipStream_t stream) {
    const float* in = (const float*)d_in[0];
    float* out = (float*)d_out;
    dim3 grid(W / TW, H / TH, D / DCHUNK);    // 8 x 32 x 8 = 2048 blocks
    dim3 block(16, 16, 1);
    hipLaunchKernelGGL(peak3d_kernel, grid, block, 0, stream, in, out);
}

// Round 2
// 118.464 us; speedup vs baseline: 2.0767x; 2.0767x over previous
//
#include <hip/hip_runtime.h>
#include <stdint.h>

// PostProcessor3D: threshold(>0.9) + 5x5x5 stride-1 maxpool + strict-local-max
// mask on [64,512,512] fp32.
//
// R13: occupancy WITHOUT spills (R12 lesson: __launch_bounds__(256,8) drove
// the allocator to a 32-reg budget -> 457 MB scratch traffic; but 85%
// occupancy DID lift realized BW to 3.6 TB/s -> residency is the right lever).
//  (a) global_load_lds DMA staging: HBM->LDS direct, no pf registers
//      (-16 VGPR), no ds_write phase. LDS un-padded (lane-contiguous dest,
//      required by DMA); stride-18 rows => ~2-way read conflicts (free).
//  (b) clamp-replicate: max over edge-replicated rows/slices == max over the
//      valid window. Clamp dd/gh/gw -> every lane issues exactly 2 DMA loads
//      every slice (trash lanes duplicate slot 359, coalesced L2 hit),
//      uniform vmcnt, zero predication. W-edge halo quads (replication
//      shifts by 4 there) fixed by zeroing f2/f3/f8/f9 at w0==0/448.
//  (c) register diet: cen ring 5->2 (read-before-write, same parity), halo
//      H-max as 5x ds_read_b64 (10 regs) in a tx==0/15 branch after the hv
//      fold (reuses dead regs). Persistent ~36, peak ~60.
//  (d) __attribute__((amdgpu_num_vgpr(64))): direct cap, no waves/EU math.
//  (e) counted wait: s_waitcnt vmcnt(1) lgkmcnt(0) + s_barrier per slice
//      (leaves this iter's store in flight, drains dist-1 prefetch DMAs).
//  (f) DCHUNK=8 -> 2048 blocks; CU c gets bids c, c+256, ..., c+1792 = all
//      8 z-chunks of one (x,y) column -> z-halo slices L1/L2-shared.
//
// Tile: W=64 x H=16, DCHUNK=8 -> grid 8x32x8 = 2048 blocks, 8/CU.

#define THRESH 0.9f

constexpr int D = 64, H = 512, W = 512;
constexpr int HW = H * W;
constexpr int TW = 64;                    // tile width in floats
constexpr int TH = 16;                    // tile height
constexpr int DCHUNK = 8;                 // depth outputs per block
constexpr int HALO = 2;
constexpr int LROWS = TH + 2 * HALO;      // 20 staged rows
constexpr int RAWQ  = TW / 4 + 2;         // 18 quads/row (NO pad: DMA dest)
constexpr int NQ = LROWS * RAWQ;          // 360 real quads
constexpr int QCAP = 512;                 // padded cap (DMA lane rigidity)
constexpr int NS = DCHUNK + 2 * HALO;     // 12 slices per block

typedef float floatx4 __attribute__((ext_vector_type(4)));
using gu32p = const __attribute__((address_space(1))) uint32_t*;
using lu32p = __attribute__((address_space(3))) uint32_t*;

__device__ __forceinline__ float4 max4(float4 a, float4 b) {
    return make_float4(fmaxf(a.x, b.x), fmaxf(a.y, b.y),
                       fmaxf(a.z, b.z), fmaxf(a.w, b.w));
}

// 5-tap sliding max for one quad. b = own (f4..f7), f2,f3 = left neighbor's
// .z,.w; f8,f9 = right neighbor's .x,.y. out[j] = max over [4c+j-2, 4c+j+2].
__device__ __forceinline__ float4 wmax5s(float f2, float f3, float4 b,
                                         float f8, float f9) {
    const float f4 = b.x, f5 = b.y, f6 = b.z, f7 = b.w;
    const float m45 = fmaxf(f4, f5);
    const float m56 = fmaxf(f5, f6);
    const float m345 = fmaxf(f3, m45);
    const float m456 = fmaxf(f4, m56);
    const float m567 = fmaxf(m56, f7);
    const float m678 = fmaxf(fmaxf(f6, f7), f8);
    float4 r;
    r.x = fmaxf(fmaxf(f2, f6), m345);
    r.y = fmaxf(fmaxf(f3, f7), m456);
    r.z = fmaxf(fmaxf(f4, f8), m567);
    r.w = fmaxf(fmaxf(f5, f9), m678);
    return r;
}

__global__ __launch_bounds__(256)
__attribute__((amdgpu_num_vgpr(64)))
void peak3d_kernel(const float* __restrict__ in, float* __restrict__ out) {
    __shared__ float4 raw[2][QCAP];       // 2 x 8192 B = 16384 B

    const int tx = threadIdx.x;           // 0..15 (quad col)
    const int ty = threadIdx.y;           // 0..15 (row)
    const int tid = ty * 16 + tx;

    const int w0 = blockIdx.x * TW;
    const int h0 = blockIdx.y * TH;
    const int d0 = blockIdx.z * DCHUNK;

    // Staging map: 360 real quads; lanes 104..255's second slot is trash
    // (clamped to quad 359's source address -> coalesced duplicate load).
    const int q0 = tid;
    const int q1c = min(tid + 256, NQ - 1);
    const int r0 = q0 / RAWQ, c0 = q0 % RAWQ;
    const int r1 = q1c / RAWQ, c1 = q1c % RAWQ;
    const int gh0 = min(max(h0 + r0 - HALO, 0), H - 1);   // clamp-replicate
    const int gw0 = min(max(w0 + 4 * c0 - 4, 0), W - 4);
    const int gh1 = min(max(h0 + r1 - HALO, 0), H - 1);
    const int gw1 = min(max(w0 + 4 * c1 - 4, 0), W - 4);
    const int off0 = gh0 * W + gw0;
    const int off1 = gh1 * W + gw1;

    // Consume-phase indices.
    const int rbase = ty * RAWQ + tx + 1;           // + rr*RAWQ, rr=0..4
    const bool isL = (tx == 0), isR = (tx == 15);
    const bool edgeW = (isL && w0 == 0) || (isR && w0 == W - TW);
    // halo float2 index: left edge reads floats .z,.w of quad col 0;
    // right edge reads floats .x,.y of quad col 17.
    const int hbase = (ty * RAWQ + (isL ? 0 : RAWQ - 1)) * 2 + (isL ? 1 : 0);

    const float4 zero4 = make_float4(0.f, 0.f, 0.f, 0.f);
    float4 win[5];                        // HW-max ring, depth 5 (D window)
    float4 cen[2];                        // raw center ring, depth 2
#pragma unroll
    for (int k = 0; k < 5; ++k) win[k] = zero4;
    cen[0] = zero4; cen[1] = zero4;

    // Issue DMA loads for slice index t (clamped), into raw[t&1].
    auto stage = [&](int t) {
        const int dd = min(max(d0 - HALO + t, 0), D - 1);
        const float* sp = in + dd * HW;
        float4* ldsb = &raw[t & 1][0];
        __builtin_amdgcn_global_load_lds((gu32p)(sp + off0),
                                         (lu32p)(ldsb + tid), 16, 0, 0);
        __builtin_amdgcn_global_load_lds((gu32p)(sp + off1),
                                         (lu32p)(ldsb + tid + 256), 16, 0, 0);
    };

    // Prologue: slice 0 in flight, then drain + join.
    stage(0);
    asm volatile("s_waitcnt vmcnt(0) lgkmcnt(0)" ::: "memory");
    __builtin_amdgcn_s_barrier();

#pragma unroll
    for (int t = 0; t < NS; ++t) {        // fully unrolled: t constant
        const int buf = t & 1;

        if (t + 1 < NS) stage(t + 1);     // dist-1 DMA prefetch

        // ---- consume: H-max (5 rows) from LDS ----
        const float4* bp = &raw[buf][0];
        const float4 r0q = bp[rbase + 0 * RAWQ];
        const float4 r1q = bp[rbase + 1 * RAWQ];
        const float4 r2q = bp[rbase + 2 * RAWQ];  // center row (raw)
        const float4 r3q = bp[rbase + 3 * RAWQ];
        const float4 r4q = bp[rbase + 4 * RAWQ];
        const float4 hv = max4(max4(max4(r0q, r1q), max4(r3q, r4q)), r2q);

        // ---- halo H-max: only edge lanes, after hv fold (reuses regs) ----
        float2 h = make_float2(0.f, 0.f);
        if (isL || isR) {
            const float2* hp = reinterpret_cast<const float2*>(bp);
            const float2 e0 = hp[hbase + 0 * RAWQ * 2];
            const float2 e1 = hp[hbase + 1 * RAWQ * 2];
            const float2 e2 = hp[hbase + 2 * RAWQ * 2];
            const float2 e3 = hp[hbase + 3 * RAWQ * 2];
            const float2 e4 = hp[hbase + 4 * RAWQ * 2];
            h.x = fmaxf(fmaxf(fmaxf(e0.x, e1.x), fmaxf(e3.x, e4.x)), e2.x);
            h.y = fmaxf(fmaxf(fmaxf(e0.y, e1.y), fmaxf(e3.y, e4.y)), e2.y);
            if (edgeW) { h.x = 0.f; h.y = 0.f; }   // true OOB in W: pad with 0
        }

        // ---- W-max via shuffles on H-maxed quads ----
        float f2 = __shfl_up(hv.z, 1);
        float f3 = __shfl_up(hv.w, 1);
        float f8 = __shfl_down(hv.x, 1);
        float f9 = __shfl_down(hv.y, 1);
        if (isL) { f2 = h.x; f3 = h.y; }
        if (isR) { f8 = h.x; f9 = h.y; }

        win[t % 5] = wmax5s(f2, f3, hv, f8, f9);   // HW-max, slice t

        // ---- D-max + strict-local-max + store (center = slice t-2) ----
        if (t >= 4) {
            const int dout = d0 + (t - 4);
            const float4 mp = max4(max4(max4(win[0], win[1]),
                                        max4(win[2], win[3])), win[4]);
            const float4 c = cen[t & 1];           // written at iter t-2
            floatx4 res;
            res.x = (c.x > THRESH && mp.x == c.x) ? c.x : 0.f;
            res.y = (c.y > THRESH && mp.y == c.y) ? c.y : 0.f;
            res.z = (c.z > THRESH && mp.z == c.z) ? c.z : 0.f;
            res.w = (c.w > THRESH && mp.w == c.w) ? c.w : 0.f;
            floatx4* op = reinterpret_cast<floatx4*>(
                out + (size_t)(dout * HW + (h0 + ty) * W + (w0 + 4 * tx)));
            __builtin_nontemporal_store(res, op);
        }
        cen[t & 1] = r2q;                          // write AFTER read above

        // ---- drain this iter's DMA prefetch, join ----
        if (t + 1 < NS) {
            if (t >= 4) {                 // leave our store in flight
                asm volatile("s_waitcnt vmcnt(1) lgkmcnt(0)" ::: "memory");
            } else {                      // no stores issued yet
                asm volatile("s_waitcnt vmcnt(0) lgkmcnt(0)" ::: "memory");
            }
            __builtin_amdgcn_s_barrier();
        }
    }
}

extern "C" void kernel_launch(void* const* d_in, const int* in_sizes, int n_in,
                              void* d_out, int out_size, void* d_ws, size_t ws_size,
                              hipStream_t stream) {
    const float* in = (const float*)d_in[0];
    float* out = (float*)d_out;
    dim3 grid(W / TW, H / TH, D / DCHUNK);    // 8 x 32 x 8 = 2048 blocks
    dim3 block(16, 16, 1);
    hipLaunchKernelGGL(peak3d_kernel, grid, block, 0, stream, in, out);
}